// Round 3
// baseline (8854.185 us; speedup 1.0000x reference)
//
#include <hip/hip_runtime.h>
#include <math.h>

#define NN 262144
#define EE 2097152
#define FIN 14
#define LW 128
#define TW 15

typedef unsigned short ushort_t;

static __device__ __forceinline__ float sigmoidf_(float v) { return 1.0f / (1.0f + expf(-v)); }

static __device__ __forceinline__ float bf2f(unsigned short u) {
  union { unsigned int i; float f; } v; v.i = ((unsigned int)u) << 16; return v.f;
}
static __device__ __forceinline__ unsigned short f2bf(float f) {
  union { float f; unsigned int i; } v; v.f = f;
  unsigned int r = v.i + 0x7FFF + ((v.i >> 16) & 1);  // RNE
  return (unsigned short)(r >> 16);
}
static __device__ __forceinline__ unsigned int pack2(float a, float b) {
  return ((unsigned int)f2bf(b) << 16) | (unsigned int)f2bf(a);
}

// ---------------- sel dtype probe + normalization ----------------
// bool(1B) sel: ~98% of bytes nonzero. int32 sel: ~24.5% nonzero.
__global__ void k_selprobe(const unsigned char* __restrict__ selb, int* __restrict__ flag) {
  __shared__ int cnt;
  if (threadIdx.x == 0) cnt = 0;
  __syncthreads();
  int c = 0;
  for (int i = threadIdx.x; i < 4096; i += 256) c += (selb[i] != 0) ? 1 : 0;
  atomicAdd(&cnt, c);
  __syncthreads();
  if (threadIdx.x == 0) *flag = (cnt > 3000) ? 1 : 0;  // 1 = byte-bool, 0 = int32
}

__global__ void k_norm_bool(const int* __restrict__ flag, const unsigned char* __restrict__ selb,
                            unsigned char* __restrict__ selN) {
  if (*flag != 1) return;
  int i = blockIdx.x * 256 + threadIdx.x;
  selN[i] = (selb[i] != 0) ? 1 : 0;
}

__global__ void k_norm_int(const int* __restrict__ flag, const unsigned char* __restrict__ selb,
                           unsigned char* __restrict__ selN) {
  if (*flag != 0) return;
  int i = blockIdx.x * 256 + threadIdx.x;
  selN[i] = (((const int*)selb)[i] != 0) ? 1 : 0;
}

// ---------------- degree ----------------
__global__ void k_deg(const int* __restrict__ ei, int* __restrict__ deg) {
  int e = blockIdx.x * 256 + threadIdx.x;
  if (e < EE) atomicAdd(&deg[ei[EE + e]], 1);
}

// ---------------- scan (exclusive prefix over deg -> row_start) ----------------
__global__ void k_scan_partial(const int* __restrict__ deg, int* __restrict__ btot) {
  __shared__ int sd[256];
  int t = threadIdx.x, b = blockIdx.x;
  int i0 = b * 1024 + t * 4;
  int s = deg[i0] + deg[i0 + 1] + deg[i0 + 2] + deg[i0 + 3];
  sd[t] = s; __syncthreads();
  for (int off = 1; off < 256; off <<= 1) {
    int x = (t >= off) ? sd[t - off] : 0;
    __syncthreads(); sd[t] += x; __syncthreads();
  }
  if (t == 255) btot[b] = sd[255];
}

__global__ void k_scan_block(const int* __restrict__ btot, int* __restrict__ bbase, int* __restrict__ row_start) {
  __shared__ int sd[256];
  int t = threadIdx.x;
  int v = btot[t];
  sd[t] = v; __syncthreads();
  for (int off = 1; off < 256; off <<= 1) {
    int x = (t >= off) ? sd[t - off] : 0;
    __syncthreads(); sd[t] += x; __syncthreads();
  }
  bbase[t] = sd[t] - v;
  if (t == 255) row_start[NN] = sd[255];
}

__global__ void k_scan_final(const int* __restrict__ deg, const int* __restrict__ bbase,
                             int* __restrict__ row_start, float* __restrict__ inv_deg,
                             float* __restrict__ dinv) {
  __shared__ int sd[256];
  int t = threadIdx.x, b = blockIdx.x;
  int i0 = b * 1024 + t * 4;
  int d0 = deg[i0], d1 = deg[i0 + 1], d2 = deg[i0 + 2], d3 = deg[i0 + 3];
  int s = d0 + d1 + d2 + d3;
  sd[t] = s; __syncthreads();
  for (int off = 1; off < 256; off <<= 1) {
    int x = (t >= off) ? sd[t - off] : 0;
    __syncthreads(); sd[t] += x; __syncthreads();
  }
  int base = bbase[b] + sd[t] - s;
  row_start[i0]     = base;
  row_start[i0 + 1] = base + d0;
  row_start[i0 + 2] = base + d0 + d1;
  row_start[i0 + 3] = base + d0 + d1 + d2;
  int dd[4] = {d0, d1, d2, d3};
  for (int j = 0; j < 4; ++j) {
    float df = (float)dd[j];
    inv_deg[i0 + j] = 1.0f / fmaxf(df, 1.0f);
    dinv[i0 + j] = (dd[j] > 0) ? rsqrtf(fmaxf(df, 1.0f)) : 0.0f;
  }
}

// ---------------- CSR fill ----------------
__global__ void k_fill(const int* __restrict__ ei, const int* __restrict__ row_start,
                       int* __restrict__ cursor, const float* __restrict__ dinv,
                       int* __restrict__ csr_src, float* __restrict__ csr_norm) {
  int e = blockIdx.x * 256 + threadIdx.x;
  if (e >= EE) return;
  int s = ei[e], d = ei[EE + e];
  int pos = atomicAdd(&cursor[d], 1);
  int idx = row_start[d] + pos;
  csr_src[idx] = s;
  csr_norm[idx] = dinv[s] * dinv[d];
}

// ---------------- pad x (N x 14 -> N x 16, zeros in pad) ----------------
__global__ void k_pad_x(const float* __restrict__ x, float* __restrict__ xp) {
  int idx = blockIdx.x * 256 + threadIdx.x;   // over NN*16
  int i = idx >> 4, lane = idx & 15;
  xp[idx] = (lane < FIN) ? x[(size_t)i * FIN + lane] : 0.0f;
}

// ---------------- width-16 mean aggregation (SAGE layer 1) ----------------
__global__ void k_prop16_mean(const float* __restrict__ h, float* __restrict__ out,
                              const int* __restrict__ row_start, const int* __restrict__ csr_src,
                              const float* __restrict__ inv_deg) {
  int t = threadIdx.x;
  int g = blockIdx.x * 16 + (t >> 4);
  int lane = t & 15;
  int s0 = row_start[g], s1 = row_start[g + 1];
  float s = 0.0f;
  for (int e = s0; e < s1; ++e) s += h[(size_t)csr_src[e] * 16 + lane];
  out[(size_t)g * 16 + lane] = s * inv_deg[g];
}

// ---------------- SAGE layer-1 GEMM: H = sigmoid(agg16@W1 + xp@W2 + b), bf16 out ----------------
__global__ __launch_bounds__(256) void k_gemm_small(
    const float* __restrict__ A1, const float* __restrict__ A2,
    const float* __restrict__ W1, const float* __restrict__ W2,
    const float* __restrict__ bias, ushort_t* __restrict__ out) {
  __shared__ float W1s[FIN][LW];
  __shared__ float W2s[FIN][LW];
  int t = threadIdx.x;
  for (int idx = t; idx < FIN * LW; idx += 256) {
    W1s[idx / LW][idx % LW] = W1[idx];
    W2s[idx / LW][idx % LW] = W2[idx];
  }
  __syncthreads();
  int node = blockIdx.x * 4 + (t >> 6);
  int lane = t & 63;
  float a1 = (lane < 16) ? A1[(size_t)node * 16 + lane] : 0.0f;
  float a2 = (lane < 16) ? A2[(size_t)node * 16 + lane] : 0.0f;
  float acc0 = bias[lane], acc1 = bias[lane + 64];
  #pragma unroll
  for (int f = 0; f < FIN; ++f) {
    float v1 = __shfl(a1, f);
    float v2 = __shfl(a2, f);
    acc0 += v1 * W1s[f][lane]      + v2 * W2s[f][lane];
    acc1 += v1 * W1s[f][lane + 64] + v2 * W2s[f][lane + 64];
  }
  out[(size_t)node * LW + lane]      = f2bf(sigmoidf_(acc0));
  out[(size_t)node * LW + lane + 64] = f2bf(sigmoidf_(acc1));
}

// ---------------- width-128 mean aggregation, bf16 in/out ----------------
__global__ void k_prop128(const ushort_t* __restrict__ h, ushort_t* __restrict__ out,
                          const int* __restrict__ row_start, const int* __restrict__ csr_src,
                          const float* __restrict__ inv_deg) {
  int t = threadIdx.x;
  int g = blockIdx.x * 4 + (t >> 6);
  int lane = t & 63;
  int s0 = row_start[g], s1 = row_start[g + 1];
  float a0 = 0.0f, a1 = 0.0f;
  for (int e = s0; e < s1; ++e) {
    unsigned int u = *(const unsigned int*)(h + (size_t)csr_src[e] * LW + 2 * lane);
    a0 += bf2f((unsigned short)(u & 0xFFFF));
    a1 += bf2f((unsigned short)(u >> 16));
  }
  float idg = inv_deg[g];
  *(unsigned int*)(out + (size_t)g * LW + 2 * lane) = pack2(a0 * idg, a1 * idg);
}

// ---------------- middle SAGE GEMM: out = sigmoid(A1@W1 + A2@W2 + b), bf16 A/out, in-place ok ----
__global__ __launch_bounds__(256) void k_gemm128(
    const ushort_t* __restrict__ A1, const ushort_t* __restrict__ A2,
    const float* __restrict__ W1, const float* __restrict__ W2,
    const float* __restrict__ bias, ushort_t* __restrict__ out) {
  __shared__ float As[32][132];   // transposed A tile: As[k][row]
  __shared__ float Bs[32][132];   // Bs[k][col]
  int tid = threadIdx.x;
  size_t row0 = (size_t)blockIdx.x * 128;
  int tr = (tid >> 4) * 8;       // 8 rows per thread
  int c0 = (tid & 15) * 4;       // cols c0..c0+3 and 64+c0..64+c0+3
  float acc[8][8];
  #pragma unroll
  for (int i = 0; i < 8; ++i)
    #pragma unroll
    for (int j = 0; j < 8; ++j) acc[i][j] = 0.0f;

  for (int phase = 0; phase < 2; ++phase) {
    const ushort_t* A = phase ? A2 : A1;
    const float* W = phase ? W2 : W1;
    for (int kc = 0; kc < 128; kc += 32) {
      // stage A tile (128 rows x 32 k), bf16 -> f32, transposed into As[k][row]
      {
        int r = tid >> 1, c = (tid & 1) * 16;
        const ushort_t* src = A + (row0 + r) * LW + kc + c;
        uint4 u0 = ((const uint4*)src)[0];
        uint4 u1 = ((const uint4*)src)[1];
        unsigned int uu[8] = {u0.x, u0.y, u0.z, u0.w, u1.x, u1.y, u1.z, u1.w};
        #pragma unroll
        for (int j = 0; j < 8; ++j) {
          As[c + 2 * j][r]     = bf2f((unsigned short)(uu[j] & 0xFFFF));
          As[c + 2 * j + 1][r] = bf2f((unsigned short)(uu[j] >> 16));
        }
      }
      // stage B tile (32 k x 128 cols), fp32
      {
        int r = tid >> 3, c = (tid & 7) * 16;
        const float* src = W + (size_t)(kc + r) * LW + c;
        float4 v0 = ((const float4*)src)[0];
        float4 v1 = ((const float4*)src)[1];
        float4 v2 = ((const float4*)src)[2];
        float4 v3 = ((const float4*)src)[3];
        *(float4*)&Bs[r][c + 0]  = v0;
        *(float4*)&Bs[r][c + 4]  = v1;
        *(float4*)&Bs[r][c + 8]  = v2;
        *(float4*)&Bs[r][c + 12] = v3;
      }
      __syncthreads();
      #pragma unroll 8
      for (int k = 0; k < 32; ++k) {
        float4 a01 = *(const float4*)&As[k][tr];
        float4 a23 = *(const float4*)&As[k][tr + 4];
        float4 b0 = *(const float4*)&Bs[k][c0];
        float4 b1 = *(const float4*)&Bs[k][64 + c0];
        float a[8] = {a01.x, a01.y, a01.z, a01.w, a23.x, a23.y, a23.z, a23.w};
        #pragma unroll
        for (int i = 0; i < 8; ++i) {
          acc[i][0] += a[i] * b0.x; acc[i][1] += a[i] * b0.y;
          acc[i][2] += a[i] * b0.z; acc[i][3] += a[i] * b0.w;
          acc[i][4] += a[i] * b1.x; acc[i][5] += a[i] * b1.y;
          acc[i][6] += a[i] * b1.z; acc[i][7] += a[i] * b1.w;
        }
      }
      __syncthreads();
    }
  }
  #pragma unroll
  for (int i = 0; i < 8; ++i) {
    size_t row = row0 + tr + i;
    float o0 = sigmoidf_(acc[i][0] + bias[c0 + 0]);
    float o1 = sigmoidf_(acc[i][1] + bias[c0 + 1]);
    float o2 = sigmoidf_(acc[i][2] + bias[c0 + 2]);
    float o3 = sigmoidf_(acc[i][3] + bias[c0 + 3]);
    float o4 = sigmoidf_(acc[i][4] + bias[64 + c0 + 0]);
    float o5 = sigmoidf_(acc[i][5] + bias[64 + c0 + 1]);
    float o6 = sigmoidf_(acc[i][6] + bias[64 + c0 + 2]);
    float o7 = sigmoidf_(acc[i][7] + bias[64 + c0 + 3]);
    uint2 w0 = make_uint2(pack2(o0, o1), pack2(o2, o3));
    uint2 w1 = make_uint2(pack2(o4, o5), pack2(o6, o7));
    *(uint2*)&out[row * LW + c0]      = w0;
    *(uint2*)&out[row * LW + 64 + c0] = w1;
  }
}

// ---------------- SAGE layer 6: width-1 transforms then aggregate ----------------
__global__ void k_wide_to1(const ushort_t* __restrict__ H, const float* __restrict__ Wl3,
                           const float* __restrict__ Wr3, float* __restrict__ g_l,
                           float* __restrict__ g_r) {
  int wave = (blockIdx.x * 256 + threadIdx.x) >> 6;
  int lane = threadIdx.x & 63;
  unsigned int u = *(const unsigned int*)(H + (size_t)wave * LW + 2 * lane);
  float h0 = bf2f((unsigned short)(u & 0xFFFF));
  float h1 = bf2f((unsigned short)(u >> 16));
  float al = h0 * Wl3[2 * lane] + h1 * Wl3[2 * lane + 1];
  float ar = h0 * Wr3[2 * lane] + h1 * Wr3[2 * lane + 1];
  #pragma unroll
  for (int off = 32; off; off >>= 1) {
    al += __shfl_xor(al, off);
    ar += __shfl_xor(ar, off);
  }
  if (lane == 0) { g_l[wave] = al; g_r[wave] = ar; }
}

__global__ void k_sage_final(const float* __restrict__ g_l, const float* __restrict__ g_r,
                             const float* __restrict__ b3, const int* __restrict__ row_start,
                             const int* __restrict__ csr_src, const float* __restrict__ inv_deg,
                             float* __restrict__ x1) {
  int i = blockIdx.x * 256 + threadIdx.x;
  int s0 = row_start[i], s1 = row_start[i + 1];
  float s = 0.0f;
  for (int e = s0; e < s1; ++e) s += g_l[csr_src[e]];
  float v = s * inv_deg[i] + g_r[i] + b3[0];
  x1[i] = fmaxf(v, 0.0f);
}

// ---------------- TAG: acc = IN @ W[0] ----------------
__global__ void k_tag_init(const float* __restrict__ h, const float* __restrict__ W,
                           float* __restrict__ acc, int win) {
  __shared__ float Ws[16][16];
  int t = threadIdx.x;
  { int r = t >> 4, c = t & 15; Ws[r][c] = (r < win && c < TW) ? W[r * TW + c] : 0.0f; }
  __syncthreads();
  int g = blockIdx.x * 16 + (t >> 4);
  int lane = t & 15;
  float v = h[(size_t)g * 16 + lane];
  float a = 0.0f;
  for (int f = 0; f < win; ++f) a += __shfl(v, f, 16) * Ws[f][lane];
  acc[(size_t)g * 16 + lane] = a;
}

// ---------------- TAG fused hop: hn = P h ; acc += hn @ Wk ----------------
__global__ void k_tag_hop(const float* __restrict__ h, float* __restrict__ hn,
                          float* __restrict__ acc, const float* __restrict__ W, int win,
                          const int* __restrict__ row_start, const int* __restrict__ csr_src,
                          const float* __restrict__ csr_norm) {
  __shared__ float Ws[16][16];
  int t = threadIdx.x;
  { int r = t >> 4, c = t & 15; Ws[r][c] = (r < win && c < TW) ? W[r * TW + c] : 0.0f; }
  __syncthreads();
  int g = blockIdx.x * 16 + (t >> 4);
  int lane = t & 15;
  int s0 = row_start[g], s1 = row_start[g + 1];
  float s = 0.0f;
  for (int e = s0; e < s1; ++e) s += csr_norm[e] * h[(size_t)csr_src[e] * 16 + lane];
  hn[(size_t)g * 16 + lane] = s;
  float a = 0.0f;
  for (int f = 0; f < win; ++f) a += __shfl(s, f, 16) * Ws[f][lane];
  acc[(size_t)g * 16 + lane] += a;
}

// ---------------- sigmoid(acc + bias), keep pad lane zero ----------------
__global__ void k_sigmoid16(const float* __restrict__ acc, const float* __restrict__ bt,
                            float* __restrict__ out) {
  int idx = blockIdx.x * 256 + threadIdx.x;   // over NN*16
  int lane = idx & 15;
  float v = acc[idx];
  out[idx] = (lane < TW) ? sigmoidf_(v + bt[lane]) : 0.0f;
}

// ---------------- TAG layer 6: g_k = T @ Wt3[k], stored k-major ----------------
__global__ void k_tag_g(const float* __restrict__ T, const float* __restrict__ Wt3,
                        float* __restrict__ gT) {
  __shared__ float Ws[16 * TW];
  int t = threadIdx.x;
  if (t < 16 * TW) Ws[t] = Wt3[t];
  __syncthreads();
  int i = blockIdx.x * 256 + t;
  const float* tr = T + (size_t)i * 16;
  float row[TW];
  #pragma unroll
  for (int f = 0; f < TW; ++f) row[f] = tr[f];
  #pragma unroll
  for (int k = 0; k < 16; ++k) {
    float a = 0.0f;
    #pragma unroll
    for (int f = 0; f < TW; ++f) a += row[f] * Ws[k * TW + f];
    gT[(size_t)k * NN + i] = a;
  }
}

// ---------------- Horner width-1 hop: snew = gk + P sold ----------------
__global__ void k_horner(const float* __restrict__ gk, const float* __restrict__ sold,
                         float* __restrict__ snew, const int* __restrict__ row_start,
                         const int* __restrict__ csr_src, const float* __restrict__ csr_norm) {
  int i = blockIdx.x * 256 + threadIdx.x;
  int s0 = row_start[i], s1 = row_start[i + 1];
  float s = 0.0f;
  for (int e = s0; e < s1; ++e) s += csr_norm[e] * sold[csr_src[e]];
  snew[i] = gk[i] + s;
}

// ---------------- final combine ----------------
__global__ void k_combine(const float* __restrict__ x1, const float* __restrict__ s,
                          const int* __restrict__ y, const unsigned char* __restrict__ selN,
                          const float* __restrict__ Wlin, const float* __restrict__ blin,
                          const float* __restrict__ bt3, float* __restrict__ out) {
  int i = blockIdx.x * 256 + threadIdx.x;
  float x3 = fmaxf(s[i] + bt3[0], 0.0f);
  float v = fmaxf(x1[i] * Wlin[0] + x3 * Wlin[1] + blin[0], 0.0f);
  bool z = (selN[i] != 0) && (y[i] == 0);
  out[i] = z ? 0.0f : v;
}

extern "C" void kernel_launch(void* const* d_in, const int* in_sizes, int n_in,
                              void* d_out, int out_size, void* d_ws, size_t ws_size,
                              hipStream_t stream) {
  const float* x    = (const float*)d_in[0];
  const int*   ei   = (const int*)d_in[1];
  const int*   y    = (const int*)d_in[2];
  const unsigned char* sel = (const unsigned char*)d_in[3];
  const float* Wl1  = (const float*)d_in[4];
  const float* Wr1  = (const float*)d_in[5];
  const float* b1   = (const float*)d_in[6];
  const float* Wl2  = (const float*)d_in[7];
  const float* Wr2  = (const float*)d_in[8];
  const float* b2   = (const float*)d_in[9];
  const float* Wl3  = (const float*)d_in[10];
  const float* Wr3  = (const float*)d_in[11];
  const float* b3   = (const float*)d_in[12];
  const float* Wt1  = (const float*)d_in[13];
  const float* bt1  = (const float*)d_in[14];
  const float* Wt2  = (const float*)d_in[15];
  const float* bt2  = (const float*)d_in[16];
  const float* Wt3  = (const float*)d_in[17];
  const float* bt3  = (const float*)d_in[18];
  const float* Wlin = (const float*)d_in[19];
  const float* blin = (const float*)d_in[20];

  const size_t MB = 1 << 20;
  unsigned char* w8 = (unsigned char*)d_ws;
  // --- compact layout, peak 176 MiB ---
  int*   deg       = (int*)(w8 + 0 * MB);       // 1 MiB
  int*   cursor    = (int*)(w8 + 1 * MB);       // 1 MiB
  int*   row_start = (int*)(w8 + 2 * MB);       // N+1 ints (<2 MiB)
  float* inv_deg   = (float*)(w8 + 4 * MB);
  float* dinv      = (float*)(w8 + 5 * MB);
  float* x1        = (float*)(w8 + 6 * MB);
  float* g_l       = (float*)(w8 + 7 * MB);
  float* g_r       = (float*)(w8 + 8 * MB);
  int*   btot      = (int*)(w8 + 9 * MB);
  int*   bbase     = (int*)(w8 + 9 * MB + 4096);
  int*   selflag   = (int*)(w8 + 9 * MB + 8192);
  float* sA        = (float*)(w8 + 10 * MB);
  float* sB        = (float*)(w8 + 11 * MB);
  unsigned char* selN = (unsigned char*)(w8 + 12 * MB);  // N bytes
  int*   csr_src   = (int*)(w8 + 16 * MB);      // 8 MiB
  float* csr_norm  = (float*)(w8 + 24 * MB);    // 8 MiB
  float* xp        = (float*)(w8 + 32 * MB);    // 16 MiB (N x 16 fp32)
  ushort_t* H      = (ushort_t*)(w8 + 48 * MB); // 64 MiB (N x 128 bf16)
  ushort_t* AGG    = (ushort_t*)(w8 + 112 * MB);// 64 MiB  -> peak = 176 MiB
  // TAG fp32 buffers overlay the H/AGG region after SAGE completes
  float* T0   = (float*)(w8 + 48 * MB);         // 16 MiB each
  float* T1   = (float*)(w8 + 64 * MB);
  float* ACC  = (float*)(w8 + 80 * MB);
  float* PA   = (float*)(w8 + 96 * MB);
  float* PB   = (float*)(w8 + 112 * MB);
  float* gT   = (float*)(w8 + 128 * MB);        // 16 MiB (16 x N)

  // ---- sel dtype normalization ----
  k_selprobe<<<1, 256, 0, stream>>>(sel, selflag);
  k_norm_bool<<<NN / 256, 256, 0, stream>>>(selflag, sel, selN);
  k_norm_int<<<NN / 256, 256, 0, stream>>>(selflag, sel, selN);

  // ---- graph preprocessing ----
  hipMemsetAsync(w8, 0, 2 * MB, stream);  // deg + cursor
  k_deg<<<EE / 256, 256, 0, stream>>>(ei, deg);
  k_scan_partial<<<256, 256, 0, stream>>>(deg, btot);
  k_scan_block<<<1, 256, 0, stream>>>(btot, bbase, row_start);
  k_scan_final<<<256, 256, 0, stream>>>(deg, bbase, row_start, inv_deg, dinv);
  k_fill<<<EE / 256, 256, 0, stream>>>(ei, row_start, cursor, dinv, csr_src, csr_norm);
  k_pad_x<<<NN * 16 / 256, 256, 0, stream>>>(x, xp);

  // ---- SAGE branch ----
  float* agg16 = gT;  // gT region is free until TAG layer 6
  k_prop16_mean<<<NN / 16, 256, 0, stream>>>(xp, agg16, row_start, csr_src, inv_deg);
  k_gemm_small<<<NN / 4, 256, 0, stream>>>(agg16, xp, Wl1, Wr1, b1, H);
  for (int l = 0; l < 4; ++l) {
    k_prop128<<<NN / 4, 256, 0, stream>>>(H, AGG, row_start, csr_src, inv_deg);
    k_gemm128<<<NN / 128, 256, 0, stream>>>(AGG, H, Wl2, Wr2, b2, H);
  }
  k_wide_to1<<<NN / 4, 256, 0, stream>>>(H, Wl3, Wr3, g_l, g_r);
  k_sage_final<<<NN / 256, 256, 0, stream>>>(g_l, g_r, b3, row_start, csr_src, inv_deg, x1);

  // ---- TAG branch (overlays H/AGG region; xp still intact) ----
  // layer 1 (win=14), weights Wt1: (16,14,15)
  {
    k_tag_init<<<NN / 16, 256, 0, stream>>>(xp, Wt1, ACC, FIN);
    const float* hc = xp;
    float* hn = PA;
    for (int k = 1; k <= 15; ++k) {
      k_tag_hop<<<NN / 16, 256, 0, stream>>>(hc, hn, ACC, Wt1 + (size_t)k * FIN * TW, FIN,
                                             row_start, csr_src, csr_norm);
      hc = hn; hn = (hn == PA) ? PB : PA;
    }
    k_sigmoid16<<<NN * 16 / 256, 256, 0, stream>>>(ACC, bt1, T0);
  }
  // layers 2-5 (win=15), weights Wt2: (16,15,15)
  float* tin = T0; float* tout = T1;
  for (int l = 0; l < 4; ++l) {
    k_tag_init<<<NN / 16, 256, 0, stream>>>(tin, Wt2, ACC, TW);
    const float* hc = tin;
    float* hn = PA;
    for (int k = 1; k <= 15; ++k) {
      k_tag_hop<<<NN / 16, 256, 0, stream>>>(hc, hn, ACC, Wt2 + (size_t)k * TW * TW, TW,
                                             row_start, csr_src, csr_norm);
      hc = hn; hn = (hn == PA) ? PB : PA;
    }
    k_sigmoid16<<<NN * 16 / 256, 256, 0, stream>>>(ACC, bt2, tout);
    float* tmp = tin; tin = tout; tout = tmp;
  }
  // layer 6: g_k = T @ Wt3[k], then Horner: s = g0 + P(g1 + P(... + P g15))
  k_tag_g<<<NN / 256, 256, 0, stream>>>(tin, Wt3, gT);
  const float* sold = gT + (size_t)15 * NN;
  float* snew = sA;
  for (int k = 14; k >= 0; --k) {
    k_horner<<<NN / 256, 256, 0, stream>>>(gT + (size_t)k * NN, sold, snew,
                                           row_start, csr_src, csr_norm);
    sold = snew; snew = (snew == sA) ? sB : sA;
  }

  // ---- combine ----
  k_combine<<<NN / 256, 256, 0, stream>>>(x1, sold, y, selN, Wlin, blin, bt3, (float*)d_out);
}

// Round 4
// 8017.761 us; speedup vs baseline: 1.1043x; 1.1043x over previous
//
#include <hip/hip_runtime.h>
#include <math.h>

#define NN 262144
#define EE 2097152
#define FIN 14
#define LW 128
#define TW 15

typedef unsigned short ushort_t;
typedef __attribute__((ext_vector_type(8))) short bf16x8v;
typedef __attribute__((ext_vector_type(4))) float f32x4v;

static __device__ __forceinline__ float sigmoidf_(float v) { return 1.0f / (1.0f + expf(-v)); }

static __device__ __forceinline__ float bf2f(unsigned short u) {
  union { unsigned int i; float f; } v; v.i = ((unsigned int)u) << 16; return v.f;
}
static __device__ __forceinline__ unsigned short f2bf(float f) {
  union { float f; unsigned int i; } v; v.f = f;
  unsigned int r = v.i + 0x7FFF + ((v.i >> 16) & 1);  // RNE
  return (unsigned short)(r >> 16);
}
static __device__ __forceinline__ unsigned int pack2(float a, float b) {
  return ((unsigned int)f2bf(b) << 16) | (unsigned int)f2bf(a);
}

// ---------------- sel dtype probe + normalization ----------------
__global__ void k_selprobe(const unsigned char* __restrict__ selb, int* __restrict__ flag) {
  __shared__ int cnt;
  if (threadIdx.x == 0) cnt = 0;
  __syncthreads();
  int c = 0;
  for (int i = threadIdx.x; i < 4096; i += 256) c += (selb[i] != 0) ? 1 : 0;
  atomicAdd(&cnt, c);
  __syncthreads();
  if (threadIdx.x == 0) *flag = (cnt > 3000) ? 1 : 0;  // 1 = byte-bool, 0 = int32
}

__global__ void k_norm_bool(const int* __restrict__ flag, const unsigned char* __restrict__ selb,
                            unsigned char* __restrict__ selN) {
  if (*flag != 1) return;
  int i = blockIdx.x * 256 + threadIdx.x;
  selN[i] = (selb[i] != 0) ? 1 : 0;
}

__global__ void k_norm_int(const int* __restrict__ flag, const unsigned char* __restrict__ selb,
                           unsigned char* __restrict__ selN) {
  if (*flag != 0) return;
  int i = blockIdx.x * 256 + threadIdx.x;
  selN[i] = (((const int*)selb)[i] != 0) ? 1 : 0;
}

// ---------------- degree ----------------
__global__ void k_deg(const int* __restrict__ ei, int* __restrict__ deg) {
  int e = blockIdx.x * 256 + threadIdx.x;
  if (e < EE) atomicAdd(&deg[ei[EE + e]], 1);
}

// ---------------- scan ----------------
__global__ void k_scan_partial(const int* __restrict__ deg, int* __restrict__ btot) {
  __shared__ int sd[256];
  int t = threadIdx.x, b = blockIdx.x;
  int i0 = b * 1024 + t * 4;
  int s = deg[i0] + deg[i0 + 1] + deg[i0 + 2] + deg[i0 + 3];
  sd[t] = s; __syncthreads();
  for (int off = 1; off < 256; off <<= 1) {
    int x = (t >= off) ? sd[t - off] : 0;
    __syncthreads(); sd[t] += x; __syncthreads();
  }
  if (t == 255) btot[b] = sd[255];
}

__global__ void k_scan_block(const int* __restrict__ btot, int* __restrict__ bbase, int* __restrict__ row_start) {
  __shared__ int sd[256];
  int t = threadIdx.x;
  int v = btot[t];
  sd[t] = v; __syncthreads();
  for (int off = 1; off < 256; off <<= 1) {
    int x = (t >= off) ? sd[t - off] : 0;
    __syncthreads(); sd[t] += x; __syncthreads();
  }
  bbase[t] = sd[t] - v;
  if (t == 255) row_start[NN] = sd[255];
}

__global__ void k_scan_final(const int* __restrict__ deg, const int* __restrict__ bbase,
                             int* __restrict__ row_start, float* __restrict__ inv_deg,
                             float* __restrict__ dinv) {
  __shared__ int sd[256];
  int t = threadIdx.x, b = blockIdx.x;
  int i0 = b * 1024 + t * 4;
  int d0 = deg[i0], d1 = deg[i0 + 1], d2 = deg[i0 + 2], d3 = deg[i0 + 3];
  int s = d0 + d1 + d2 + d3;
  sd[t] = s; __syncthreads();
  for (int off = 1; off < 256; off <<= 1) {
    int x = (t >= off) ? sd[t - off] : 0;
    __syncthreads(); sd[t] += x; __syncthreads();
  }
  int base = bbase[b] + sd[t] - s;
  row_start[i0]     = base;
  row_start[i0 + 1] = base + d0;
  row_start[i0 + 2] = base + d0 + d1;
  row_start[i0 + 3] = base + d0 + d1 + d2;
  int dd[4] = {d0, d1, d2, d3};
  for (int j = 0; j < 4; ++j) {
    float df = (float)dd[j];
    inv_deg[i0 + j] = 1.0f / fmaxf(df, 1.0f);
    dinv[i0 + j] = (dd[j] > 0) ? rsqrtf(fmaxf(df, 1.0f)) : 0.0f;
  }
}

// ---------------- CSR fill (src only; norm folded into hop kernels) ----------------
__global__ void k_fill(const int* __restrict__ ei, const int* __restrict__ row_start,
                       int* __restrict__ cursor, int* __restrict__ csr_src) {
  int e = blockIdx.x * 256 + threadIdx.x;
  if (e >= EE) return;
  int s = ei[e], d = ei[EE + e];
  int pos = atomicAdd(&cursor[d], 1);
  csr_src[row_start[d] + pos] = s;
}

// ---------------- pad x: fp32 xp (SAGE) + bf16 xpb (TAG) ----------------
__global__ void k_pad_x(const float* __restrict__ x, float* __restrict__ xp,
                        ushort_t* __restrict__ xpb) {
  int idx = blockIdx.x * 256 + threadIdx.x;   // over NN*16
  int i = idx >> 4, lane = idx & 15;
  float v = (lane < FIN) ? x[(size_t)i * FIN + lane] : 0.0f;
  xp[idx] = v;
  xpb[idx] = f2bf(v);
}

// ---------------- width-16 mean aggregation (SAGE layer 1) ----------------
__global__ void k_prop16_mean(const float* __restrict__ h, float* __restrict__ out,
                              const int* __restrict__ row_start, const int* __restrict__ csr_src,
                              const float* __restrict__ inv_deg) {
  int t = threadIdx.x;
  int g = blockIdx.x * 16 + (t >> 4);
  int lane = t & 15;
  int s0 = row_start[g], s1 = row_start[g + 1];
  float s = 0.0f;
  for (int e = s0; e < s1; ++e) s += h[(size_t)csr_src[e] * 16 + lane];
  out[(size_t)g * 16 + lane] = s * inv_deg[g];
}

// ---------------- SAGE layer-1 GEMM: H = sigmoid(agg16@W1 + xp@W2 + b), bf16 out ----------------
__global__ __launch_bounds__(256) void k_gemm_small(
    const float* __restrict__ A1, const float* __restrict__ A2,
    const float* __restrict__ W1, const float* __restrict__ W2,
    const float* __restrict__ bias, ushort_t* __restrict__ out) {
  __shared__ float W1s[FIN][LW];
  __shared__ float W2s[FIN][LW];
  int t = threadIdx.x;
  for (int idx = t; idx < FIN * LW; idx += 256) {
    W1s[idx / LW][idx % LW] = W1[idx];
    W2s[idx / LW][idx % LW] = W2[idx];
  }
  __syncthreads();
  int node = blockIdx.x * 4 + (t >> 6);
  int lane = t & 63;
  float a1 = (lane < 16) ? A1[(size_t)node * 16 + lane] : 0.0f;
  float a2 = (lane < 16) ? A2[(size_t)node * 16 + lane] : 0.0f;
  float acc0 = bias[lane], acc1 = bias[lane + 64];
  #pragma unroll
  for (int f = 0; f < FIN; ++f) {
    float v1 = __shfl(a1, f);
    float v2 = __shfl(a2, f);
    acc0 += v1 * W1s[f][lane]      + v2 * W2s[f][lane];
    acc1 += v1 * W1s[f][lane + 64] + v2 * W2s[f][lane + 64];
  }
  out[(size_t)node * LW + lane]      = f2bf(sigmoidf_(acc0));
  out[(size_t)node * LW + lane + 64] = f2bf(sigmoidf_(acc1));
}

// ---------------- width-128 mean aggregation, bf16 in/out ----------------
__global__ void k_prop128(const ushort_t* __restrict__ h, ushort_t* __restrict__ out,
                          const int* __restrict__ row_start, const int* __restrict__ csr_src,
                          const float* __restrict__ inv_deg) {
  int t = threadIdx.x;
  int g = blockIdx.x * 4 + (t >> 6);
  int lane = t & 63;
  int s0 = row_start[g], s1 = row_start[g + 1];
  float a0 = 0.0f, a1 = 0.0f;
  for (int e = s0; e < s1; ++e) {
    unsigned int u = *(const unsigned int*)(h + (size_t)csr_src[e] * LW + 2 * lane);
    a0 += bf2f((unsigned short)(u & 0xFFFF));
    a1 += bf2f((unsigned short)(u >> 16));
  }
  float idg = inv_deg[g];
  *(unsigned int*)(out + (size_t)g * LW + 2 * lane) = pack2(a0 * idg, a1 * idg);
}

// ---------------- weight conversion: Wt[n][k] = (k<128 ? Wl[k][n] : Wr[k-128][n]) bf16 ----------------
__global__ void k_convW(const float* __restrict__ Wl, const float* __restrict__ Wr,
                        ushort_t* __restrict__ Wt) {
  int idx = blockIdx.x * 256 + threadIdx.x;   // over 128*256
  int n = idx >> 8, k = idx & 255;
  float v = (k < 128) ? Wl[k * 128 + n] : Wr[(k - 128) * 128 + n];
  Wt[idx] = f2bf(v);
}

// ---------------- MFMA SAGE GEMM: out = sigmoid([A1|A2] @ Wcat + b), bf16, in-place (out==A2) ----
__global__ __launch_bounds__(256) void k_gemm128_mfma(
    const ushort_t* __restrict__ A1, const ushort_t* __restrict__ A2,
    const ushort_t* __restrict__ Wt,   // [128][256] bf16, Wt[n][k]
    const float* __restrict__ bias, ushort_t* __restrict__ out) {
  int tid = threadIdx.x;
  int wave = tid >> 6, lane = tid & 63;
  int row0 = blockIdx.x * 64 + wave * 16;
  int r = lane & 15, kg = lane >> 4;   // r = row (A) / col (B,D); kg = k-group
  f32x4v acc[8];
  #pragma unroll
  for (int nt = 0; nt < 8; ++nt) acc[nt] = (f32x4v){0.f, 0.f, 0.f, 0.f};
  #pragma unroll
  for (int ks = 0; ks < 8; ++ks) {
    const ushort_t* asrc = (ks < 4)
        ? (A1 + (size_t)(row0 + r) * LW + ks * 32 + kg * 8)
        : (A2 + (size_t)(row0 + r) * LW + (ks - 4) * 32 + kg * 8);
    bf16x8v a = *(const bf16x8v*)asrc;
    #pragma unroll
    for (int nt = 0; nt < 8; ++nt) {
      bf16x8v b = *(const bf16x8v*)(Wt + (size_t)(nt * 16 + r) * 256 + ks * 32 + kg * 8);
      acc[nt] = __builtin_amdgcn_mfma_f32_16x16x32_bf16(a, b, acc[nt], 0, 0, 0);
    }
  }
  // C/D: col = lane&15 (=r), row = (lane>>4)*4 + j  [m89-verified]
  #pragma unroll
  for (int nt = 0; nt < 8; ++nt) {
    #pragma unroll
    for (int j = 0; j < 4; ++j) {
      float v = sigmoidf_(acc[nt][j] + bias[nt * 16 + r]);
      out[(size_t)(row0 + kg * 4 + j) * LW + nt * 16 + r] = f2bf(v);
    }
  }
}

// ---------------- SAGE layer 6: width-1 transforms then aggregate ----------------
__global__ void k_wide_to1(const ushort_t* __restrict__ H, const float* __restrict__ Wl3,
                           const float* __restrict__ Wr3, float* __restrict__ g_l,
                           float* __restrict__ g_r) {
  int wave = (blockIdx.x * 256 + threadIdx.x) >> 6;
  int lane = threadIdx.x & 63;
  unsigned int u = *(const unsigned int*)(H + (size_t)wave * LW + 2 * lane);
  float h0 = bf2f((unsigned short)(u & 0xFFFF));
  float h1 = bf2f((unsigned short)(u >> 16));
  float al = h0 * Wl3[2 * lane] + h1 * Wl3[2 * lane + 1];
  float ar = h0 * Wr3[2 * lane] + h1 * Wr3[2 * lane + 1];
  #pragma unroll
  for (int off = 32; off; off >>= 1) {
    al += __shfl_xor(al, off);
    ar += __shfl_xor(ar, off);
  }
  if (lane == 0) { g_l[wave] = al; g_r[wave] = ar; }
}

__global__ void k_sage_final(const float* __restrict__ g_l, const float* __restrict__ g_r,
                             const float* __restrict__ b3, const int* __restrict__ row_start,
                             const int* __restrict__ csr_src, const float* __restrict__ inv_deg,
                             float* __restrict__ x1) {
  int i = blockIdx.x * 256 + threadIdx.x;
  int s0 = row_start[i], s1 = row_start[i + 1];
  float s = 0.0f;
  for (int e = s0; e < s1; ++e) s += g_l[csr_src[e]];
  float v = s * inv_deg[i] + g_r[i] + b3[0];
  x1[i] = fmaxf(v, 0.0f);
}

// ---------------- TAG Horner hop (width 16, bf16) ----------------
// mode 0 (init,k=K):  w_out = dinv ⊙ (T·Wk)
// mode 1 (hop):       s = T·Wk + dinv·gather(w_in);  w_out = dinv ⊙ s
// mode 2 (last,k=0):  s = T·Wk + dinv·gather(w_in);  w_out = sigmoid(s + bias) (pad lane 0)
__global__ void k_tag_hh(const ushort_t* __restrict__ T, const float* __restrict__ W, int win,
                         const ushort_t* __restrict__ w_in, ushort_t* __restrict__ w_out,
                         const float* __restrict__ bias, int mode,
                         const int* __restrict__ row_start, const int* __restrict__ csr_src,
                         const float* __restrict__ dinv) {
  __shared__ float Ws[16][16];
  int t = threadIdx.x;
  { int rr = t >> 4, c = t & 15; Ws[rr][c] = (rr < win && c < TW) ? W[rr * TW + c] : 0.0f; }
  __syncthreads();
  int g = blockIdx.x * 16 + (t >> 4);
  int lane = t & 15;
  float di = dinv[g];
  float tv = bf2f(T[(size_t)g * 16 + lane]);
  float s = 0.0f;
  #pragma unroll
  for (int f = 0; f < 16; ++f) s += __shfl(tv, f, 16) * Ws[f][lane];
  if (mode != 0) {
    int e0 = row_start[g], e1 = row_start[g + 1];
    float gs = 0.0f;
    for (int e = e0; e < e1; ++e) gs += bf2f(w_in[(size_t)csr_src[e] * 16 + lane]);
    s += di * gs;
  }
  float o;
  if (mode == 2) o = (lane < TW) ? sigmoidf_(s + bias[lane]) : 0.0f;
  else           o = di * s;
  w_out[(size_t)g * 16 + lane] = f2bf(o);
}

// ---------------- TAG layer 6: g_k = T @ Wt3[k], k-major (T bf16) ----------------
__global__ void k_tag_g(const ushort_t* __restrict__ T, const float* __restrict__ Wt3,
                        float* __restrict__ gT) {
  __shared__ float Ws[16 * TW];
  int t = threadIdx.x;
  if (t < 16 * TW) Ws[t] = Wt3[t];
  __syncthreads();
  int i = blockIdx.x * 256 + t;
  const ushort_t* tr = T + (size_t)i * 16;
  float row[TW];
  #pragma unroll
  for (int f = 0; f < TW; ++f) row[f] = bf2f(tr[f]);
  #pragma unroll
  for (int k = 0; k < 16; ++k) {
    float a = 0.0f;
    #pragma unroll
    for (int f = 0; f < TW; ++f) a += row[f] * Ws[k * TW + f];
    gT[(size_t)k * NN + i] = a;
  }
}

// ---------------- layer-6 Horner init: w = dinv ⊙ g15 ----------------
__global__ void k_scale1(const float* __restrict__ g15, const float* __restrict__ dinv,
                         float* __restrict__ w) {
  int i = blockIdx.x * 256 + threadIdx.x;
  w[i] = dinv[i] * g15[i];
}

// ---------------- layer-6 Horner hop (dinv folded): s = gk + dinv·Σ w[src] ----------------
__global__ void k_horner(const float* __restrict__ gk, const float* __restrict__ w_in,
                         float* __restrict__ w_out, int last,
                         const int* __restrict__ row_start, const int* __restrict__ csr_src,
                         const float* __restrict__ dinv) {
  int i = blockIdx.x * 256 + threadIdx.x;
  int e0 = row_start[i], e1 = row_start[i + 1];
  float gs = 0.0f;
  for (int e = e0; e < e1; ++e) gs += w_in[csr_src[e]];
  float s = gk[i] + dinv[i] * gs;
  w_out[i] = last ? s : dinv[i] * s;
}

// ---------------- final combine ----------------
__global__ void k_combine(const float* __restrict__ x1, const float* __restrict__ s,
                          const int* __restrict__ y, const unsigned char* __restrict__ selN,
                          const float* __restrict__ Wlin, const float* __restrict__ blin,
                          const float* __restrict__ bt3, float* __restrict__ out) {
  int i = blockIdx.x * 256 + threadIdx.x;
  float x3 = fmaxf(s[i] + bt3[0], 0.0f);
  float v = fmaxf(x1[i] * Wlin[0] + x3 * Wlin[1] + blin[0], 0.0f);
  bool z = (selN[i] != 0) && (y[i] == 0);
  out[i] = z ? 0.0f : v;
}

extern "C" void kernel_launch(void* const* d_in, const int* in_sizes, int n_in,
                              void* d_out, int out_size, void* d_ws, size_t ws_size,
                              hipStream_t stream) {
  const float* x    = (const float*)d_in[0];
  const int*   ei   = (const int*)d_in[1];
  const int*   y    = (const int*)d_in[2];
  const unsigned char* sel = (const unsigned char*)d_in[3];
  const float* Wl1  = (const float*)d_in[4];
  const float* Wr1  = (const float*)d_in[5];
  const float* b1   = (const float*)d_in[6];
  const float* Wl2  = (const float*)d_in[7];
  const float* Wr2  = (const float*)d_in[8];
  const float* b2   = (const float*)d_in[9];
  const float* Wl3  = (const float*)d_in[10];
  const float* Wr3  = (const float*)d_in[11];
  const float* b3   = (const float*)d_in[12];
  const float* Wt1  = (const float*)d_in[13];
  const float* bt1  = (const float*)d_in[14];
  const float* Wt2  = (const float*)d_in[15];
  const float* bt2  = (const float*)d_in[16];
  const float* Wt3  = (const float*)d_in[17];
  const float* bt3  = (const float*)d_in[18];
  const float* Wlin = (const float*)d_in[19];
  const float* blin = (const float*)d_in[20];

  const size_t MB = 1 << 20;
  unsigned char* w8 = (unsigned char*)d_ws;
  int*   deg       = (int*)(w8 + 0 * MB);
  int*   cursor    = (int*)(w8 + 1 * MB);
  int*   row_start = (int*)(w8 + 2 * MB);        // N+1 ints
  float* inv_deg   = (float*)(w8 + 4 * MB);
  float* dinv      = (float*)(w8 + 5 * MB);
  float* x1        = (float*)(w8 + 6 * MB);
  float* g_l       = (float*)(w8 + 7 * MB);
  float* g_r       = (float*)(w8 + 8 * MB);
  int*   btot      = (int*)(w8 + 9 * MB);
  int*   bbase     = (int*)(w8 + 9 * MB + 4096);
  int*   selflag   = (int*)(w8 + 9 * MB + 8192);
  float* sA        = (float*)(w8 + 10 * MB);
  float* w6a       = (float*)(w8 + 11 * MB);
  float* w6b       = (float*)(w8 + 12 * MB);
  unsigned char* selN = (unsigned char*)(w8 + 13 * MB);
  ushort_t* Wtc    = (ushort_t*)(w8 + 14 * MB);  // 64 KB gemm weights
  int*   csr_src   = (int*)(w8 + 16 * MB);       // 8 MiB
  float* xp        = (float*)(w8 + 24 * MB);     // 16 MiB (N x 16 fp32)
  ushort_t* xpb    = (ushort_t*)(w8 + 40 * MB);  // 8 MiB (N x 16 bf16)
  ushort_t* H      = (ushort_t*)(w8 + 48 * MB);  // 64 MiB (N x 128 bf16)
  ushort_t* AGG    = (ushort_t*)(w8 + 112 * MB); // 64 MiB -> peak 176 MiB
  // SAGE width-16 fp32 aggregate lives at AGG start (dead until first prop128)
  float* agg16     = (float*)(w8 + 112 * MB);    // 16 MiB
  // TAG overlays (AGG region, dead after SAGE)
  ushort_t* T0  = (ushort_t*)(w8 + 112 * MB);    // 8 MiB
  ushort_t* T1  = (ushort_t*)(w8 + 120 * MB);
  ushort_t* wA  = (ushort_t*)(w8 + 128 * MB);
  ushort_t* wB  = (ushort_t*)(w8 + 136 * MB);
  float* gT     = (float*)(w8 + 144 * MB);       // 16 MiB (16 x N fp32)

  // ---- sel normalization ----
  k_selprobe<<<1, 256, 0, stream>>>(sel, selflag);
  k_norm_bool<<<NN / 256, 256, 0, stream>>>(selflag, sel, selN);
  k_norm_int<<<NN / 256, 256, 0, stream>>>(selflag, sel, selN);

  // ---- graph preprocessing ----
  hipMemsetAsync(w8, 0, 2 * MB, stream);  // deg + cursor
  k_deg<<<EE / 256, 256, 0, stream>>>(ei, deg);
  k_scan_partial<<<256, 256, 0, stream>>>(deg, btot);
  k_scan_block<<<1, 256, 0, stream>>>(btot, bbase, row_start);
  k_scan_final<<<256, 256, 0, stream>>>(deg, bbase, row_start, inv_deg, dinv);
  k_fill<<<EE / 256, 256, 0, stream>>>(ei, row_start, cursor, csr_src);
  k_pad_x<<<NN * 16 / 256, 256, 0, stream>>>(x, xp, xpb);
  k_convW<<<128, 256, 0, stream>>>(Wl2, Wr2, Wtc);

  // ---- SAGE branch ----
  k_prop16_mean<<<NN / 16, 256, 0, stream>>>(xp, agg16, row_start, csr_src, inv_deg);
  k_gemm_small<<<NN / 4, 256, 0, stream>>>(agg16, xp, Wl1, Wr1, b1, H);
  for (int l = 0; l < 4; ++l) {
    k_prop128<<<NN / 4, 256, 0, stream>>>(H, AGG, row_start, csr_src, inv_deg);
    k_gemm128_mfma<<<NN / 64, 256, 0, stream>>>(AGG, H, Wtc, b2, H);
  }
  k_wide_to1<<<NN / 4, 256, 0, stream>>>(H, Wl3, Wr3, g_l, g_r);
  k_sage_final<<<NN / 256, 256, 0, stream>>>(g_l, g_r, b3, row_start, csr_src, inv_deg, x1);

  // ---- TAG branch (Horner form; overlays AGG region; xpb intact) ----
  // layer 1: input xpb (win=14, Wt1 (16,14,15), bias bt1) -> T0
  {
    const ushort_t* T = xpb;
    k_tag_hh<<<NN / 16, 256, 0, stream>>>(T, Wt1 + (size_t)15 * FIN * TW, FIN,
                                          nullptr, wA, nullptr, 0, row_start, csr_src, dinv);
    ushort_t* wi = wA; ushort_t* wo = wB;
    for (int k = 14; k >= 1; --k) {
      k_tag_hh<<<NN / 16, 256, 0, stream>>>(T, Wt1 + (size_t)k * FIN * TW, FIN,
                                            wi, wo, nullptr, 1, row_start, csr_src, dinv);
      ushort_t* tmp = wi; wi = wo; wo = tmp;
    }
    k_tag_hh<<<NN / 16, 256, 0, stream>>>(T, Wt1, FIN, wi, T0, bt1, 2,
                                          row_start, csr_src, dinv);
  }
  // layers 2-5: win=15, Wt2 (16,15,15), bias bt2
  ushort_t* tin = T0; ushort_t* tout = T1;
  for (int l = 0; l < 4; ++l) {
    k_tag_hh<<<NN / 16, 256, 0, stream>>>(tin, Wt2 + (size_t)15 * TW * TW, TW,
                                          nullptr, wA, nullptr, 0, row_start, csr_src, dinv);
    ushort_t* wi = wA; ushort_t* wo = wB;
    for (int k = 14; k >= 1; --k) {
      k_tag_hh<<<NN / 16, 256, 0, stream>>>(tin, Wt2 + (size_t)k * TW * TW, TW,
                                            wi, wo, nullptr, 1, row_start, csr_src, dinv);
      ushort_t* tmp = wi; wi = wo; wo = tmp;
    }
    k_tag_hh<<<NN / 16, 256, 0, stream>>>(tin, Wt2, TW, wi, tout, bt2, 2,
                                          row_start, csr_src, dinv);
    ushort_t* tmp = tin; tin = tout; tout = tmp;
  }
  // layer 6: g_k = T @ Wt3[k]; Horner width-1 with folded dinv
  k_tag_g<<<NN / 256, 256, 0, stream>>>(tin, Wt3, gT);
  k_scale1<<<NN / 256, 256, 0, stream>>>(gT + (size_t)15 * NN, dinv, w6a);
  float* wi = w6a; float* wo = w6b;
  for (int k = 14; k >= 0; --k) {
    int last = (k == 0) ? 1 : 0;
    float* dst = last ? sA : wo;
    k_horner<<<NN / 256, 256, 0, stream>>>(gT + (size_t)k * NN, wi, dst, last,
                                           row_start, csr_src, dinv);
    float* tmp = wi; wi = wo; wo = tmp;
  }

  // ---- combine ----
  k_combine<<<NN / 256, 256, 0, stream>>>(x1, sA, y, selN, Wlin, blin, bt3, (float*)d_out);
}

// Round 5
// 4210.639 us; speedup vs baseline: 2.1028x; 1.9042x over previous
//
#include <hip/hip_runtime.h>
#include <math.h>

#define NN 262144
#define EE 2097152
#define FIN 14
#define LW 128
#define TW 15

typedef unsigned short ushort_t;
typedef unsigned int uint_t;
typedef __attribute__((ext_vector_type(8))) short bf16x8v;
typedef __attribute__((ext_vector_type(4))) float f32x4v;

static __device__ __forceinline__ float sigmoidf_(float v) { return 1.0f / (1.0f + expf(-v)); }

static __device__ __forceinline__ float bf2f(unsigned short u) {
  union { unsigned int i; float f; } v; v.i = ((unsigned int)u) << 16; return v.f;
}
static __device__ __forceinline__ unsigned short f2bf(float f) {
  union { float f; unsigned int i; } v; v.f = f;
  unsigned int r = v.i + 0x7FFF + ((v.i >> 16) & 1);  // RNE
  return (unsigned short)(r >> 16);
}
static __device__ __forceinline__ unsigned int pack2(float a, float b) {
  return ((unsigned int)f2bf(b) << 16) | (unsigned int)f2bf(a);
}
// add a 32B bf16 row (16 elems, as 2x uint4) into acc[0..15]
static __device__ __forceinline__ void addrow16(float* acc, uint4 u0, uint4 u1) {
  acc[0]  += bf2f((unsigned short)(u0.x & 0xFFFF)); acc[1]  += bf2f((unsigned short)(u0.x >> 16));
  acc[2]  += bf2f((unsigned short)(u0.y & 0xFFFF)); acc[3]  += bf2f((unsigned short)(u0.y >> 16));
  acc[4]  += bf2f((unsigned short)(u0.z & 0xFFFF)); acc[5]  += bf2f((unsigned short)(u0.z >> 16));
  acc[6]  += bf2f((unsigned short)(u0.w & 0xFFFF)); acc[7]  += bf2f((unsigned short)(u0.w >> 16));
  acc[8]  += bf2f((unsigned short)(u1.x & 0xFFFF)); acc[9]  += bf2f((unsigned short)(u1.x >> 16));
  acc[10] += bf2f((unsigned short)(u1.y & 0xFFFF)); acc[11] += bf2f((unsigned short)(u1.y >> 16));
  acc[12] += bf2f((unsigned short)(u1.z & 0xFFFF)); acc[13] += bf2f((unsigned short)(u1.z >> 16));
  acc[14] += bf2f((unsigned short)(u1.w & 0xFFFF)); acc[15] += bf2f((unsigned short)(u1.w >> 16));
}

// ---------------- sel dtype probe + normalization ----------------
__global__ void k_selprobe(const unsigned char* __restrict__ selb, int* __restrict__ flag) {
  __shared__ int cnt;
  if (threadIdx.x == 0) cnt = 0;
  __syncthreads();
  int c = 0;
  for (int i = threadIdx.x; i < 4096; i += 256) c += (selb[i] != 0) ? 1 : 0;
  atomicAdd(&cnt, c);
  __syncthreads();
  if (threadIdx.x == 0) *flag = (cnt > 3000) ? 1 : 0;  // 1 = byte-bool, 0 = int32
}

__global__ void k_norm_bool(const int* __restrict__ flag, const unsigned char* __restrict__ selb,
                            unsigned char* __restrict__ selN) {
  if (*flag != 1) return;
  int i = blockIdx.x * 256 + threadIdx.x;
  selN[i] = (selb[i] != 0) ? 1 : 0;
}

__global__ void k_norm_int(const int* __restrict__ flag, const unsigned char* __restrict__ selb,
                           unsigned char* __restrict__ selN) {
  if (*flag != 0) return;
  int i = blockIdx.x * 256 + threadIdx.x;
  selN[i] = (((const int*)selb)[i] != 0) ? 1 : 0;
}

// ---------------- degree ----------------
__global__ void k_deg(const int* __restrict__ ei, int* __restrict__ deg) {
  int e = blockIdx.x * 256 + threadIdx.x;
  if (e < EE) atomicAdd(&deg[ei[EE + e]], 1);
}

// ---------------- scan ----------------
__global__ void k_scan_partial(const int* __restrict__ deg, int* __restrict__ btot) {
  __shared__ int sd[256];
  int t = threadIdx.x, b = blockIdx.x;
  int i0 = b * 1024 + t * 4;
  int s = deg[i0] + deg[i0 + 1] + deg[i0 + 2] + deg[i0 + 3];
  sd[t] = s; __syncthreads();
  for (int off = 1; off < 256; off <<= 1) {
    int x = (t >= off) ? sd[t - off] : 0;
    __syncthreads(); sd[t] += x; __syncthreads();
  }
  if (t == 255) btot[b] = sd[255];
}

__global__ void k_scan_block(const int* __restrict__ btot, int* __restrict__ bbase, int* __restrict__ row_start) {
  __shared__ int sd[256];
  int t = threadIdx.x;
  int v = btot[t];
  sd[t] = v; __syncthreads();
  for (int off = 1; off < 256; off <<= 1) {
    int x = (t >= off) ? sd[t - off] : 0;
    __syncthreads(); sd[t] += x; __syncthreads();
  }
  bbase[t] = sd[t] - v;
  if (t == 255) row_start[NN] = sd[255];
}

__global__ void k_scan_final(const int* __restrict__ deg, const int* __restrict__ bbase,
                             int* __restrict__ row_start, float* __restrict__ inv_deg,
                             float* __restrict__ dinv) {
  __shared__ int sd[256];
  int t = threadIdx.x, b = blockIdx.x;
  int i0 = b * 1024 + t * 4;
  int d0 = deg[i0], d1 = deg[i0 + 1], d2 = deg[i0 + 2], d3 = deg[i0 + 3];
  int s = d0 + d1 + d2 + d3;
  sd[t] = s; __syncthreads();
  for (int off = 1; off < 256; off <<= 1) {
    int x = (t >= off) ? sd[t - off] : 0;
    __syncthreads(); sd[t] += x; __syncthreads();
  }
  int base = bbase[b] + sd[t] - s;
  row_start[i0]     = base;
  row_start[i0 + 1] = base + d0;
  row_start[i0 + 2] = base + d0 + d1;
  row_start[i0 + 3] = base + d0 + d1 + d2;
  int dd[4] = {d0, d1, d2, d3};
  for (int j = 0; j < 4; ++j) {
    float df = (float)dd[j];
    inv_deg[i0 + j] = 1.0f / fmaxf(df, 1.0f);
    dinv[i0 + j] = (dd[j] > 0) ? rsqrtf(fmaxf(df, 1.0f)) : 0.0f;
  }
}

// ---------------- CSR fill ----------------
__global__ void k_fill(const int* __restrict__ ei, const int* __restrict__ row_start,
                       int* __restrict__ cursor, int* __restrict__ csr_src) {
  int e = blockIdx.x * 256 + threadIdx.x;
  if (e >= EE) return;
  int s = ei[e], d = ei[EE + e];
  int pos = atomicAdd(&cursor[d], 1);
  csr_src[row_start[d] + pos] = s;
}

// ---------------- pad x: fp32 xp (SAGE) + bf16 xpb (TAG) ----------------
__global__ void k_pad_x(const float* __restrict__ x, float* __restrict__ xp,
                        ushort_t* __restrict__ xpb) {
  int idx = blockIdx.x * 256 + threadIdx.x;   // over NN*16
  int i = idx >> 4, lane = idx & 15;
  float v = (lane < FIN) ? x[(size_t)i * FIN + lane] : 0.0f;
  xp[idx] = v;
  xpb[idx] = f2bf(v);
}

// ---------------- width-16 mean aggregation (SAGE layer 1), thread-per-node ----------------
__global__ __launch_bounds__(256) void k_prop16_mean(
    const float* __restrict__ h, float* __restrict__ out,
    const int* __restrict__ row_start, const int* __restrict__ csr_src,
    const float* __restrict__ inv_deg) {
  int i = blockIdx.x * 256 + threadIdx.x;
  float acc[16];
  #pragma unroll
  for (int c = 0; c < 16; ++c) acc[c] = 0.0f;
  int e0 = row_start[i], e1 = row_start[i + 1];
  int e = e0;
  for (; e + 2 <= e1; e += 2) {
    int i0 = csr_src[e], i1 = csr_src[e + 1];
    const float4* r0 = (const float4*)(h + (size_t)i0 * 16);
    const float4* r1 = (const float4*)(h + (size_t)i1 * 16);
    float4 a0 = r0[0], a1 = r0[1], a2 = r0[2], a3 = r0[3];
    float4 b0 = r1[0], b1 = r1[1], b2 = r1[2], b3 = r1[3];
    acc[0]+=a0.x+b0.x; acc[1]+=a0.y+b0.y; acc[2]+=a0.z+b0.z; acc[3]+=a0.w+b0.w;
    acc[4]+=a1.x+b1.x; acc[5]+=a1.y+b1.y; acc[6]+=a1.z+b1.z; acc[7]+=a1.w+b1.w;
    acc[8]+=a2.x+b2.x; acc[9]+=a2.y+b2.y; acc[10]+=a2.z+b2.z; acc[11]+=a2.w+b2.w;
    acc[12]+=a3.x+b3.x; acc[13]+=a3.y+b3.y; acc[14]+=a3.z+b3.z; acc[15]+=a3.w+b3.w;
  }
  for (; e < e1; ++e) {
    const float4* r0 = (const float4*)(h + (size_t)csr_src[e] * 16);
    float4 a0 = r0[0], a1 = r0[1], a2 = r0[2], a3 = r0[3];
    acc[0]+=a0.x; acc[1]+=a0.y; acc[2]+=a0.z; acc[3]+=a0.w;
    acc[4]+=a1.x; acc[5]+=a1.y; acc[6]+=a1.z; acc[7]+=a1.w;
    acc[8]+=a2.x; acc[9]+=a2.y; acc[10]+=a2.z; acc[11]+=a2.w;
    acc[12]+=a3.x; acc[13]+=a3.y; acc[14]+=a3.z; acc[15]+=a3.w;
  }
  float idg = inv_deg[i];
  float4 o[4];
  #pragma unroll
  for (int q = 0; q < 4; ++q) {
    o[q].x = acc[q*4+0]*idg; o[q].y = acc[q*4+1]*idg;
    o[q].z = acc[q*4+2]*idg; o[q].w = acc[q*4+3]*idg;
  }
  float4* dst = (float4*)(out + (size_t)i * 16);
  dst[0]=o[0]; dst[1]=o[1]; dst[2]=o[2]; dst[3]=o[3];
}

// ---------------- SAGE layer-1 GEMM: H = sigmoid(agg16@W1 + xp@W2 + b), bf16 out ----------------
__global__ __launch_bounds__(256) void k_gemm_small(
    const float* __restrict__ A1, const float* __restrict__ A2,
    const float* __restrict__ W1, const float* __restrict__ W2,
    const float* __restrict__ bias, ushort_t* __restrict__ out) {
  __shared__ float W1s[FIN][LW];
  __shared__ float W2s[FIN][LW];
  int t = threadIdx.x;
  for (int idx = t; idx < FIN * LW; idx += 256) {
    W1s[idx / LW][idx % LW] = W1[idx];
    W2s[idx / LW][idx % LW] = W2[idx];
  }
  __syncthreads();
  int node = blockIdx.x * 4 + (t >> 6);
  int lane = t & 63;
  float a1 = (lane < 16) ? A1[(size_t)node * 16 + lane] : 0.0f;
  float a2 = (lane < 16) ? A2[(size_t)node * 16 + lane] : 0.0f;
  float acc0 = bias[lane], acc1 = bias[lane + 64];
  #pragma unroll
  for (int f = 0; f < FIN; ++f) {
    float v1 = __shfl(a1, f);
    float v2 = __shfl(a2, f);
    acc0 += v1 * W1s[f][lane]      + v2 * W2s[f][lane];
    acc1 += v1 * W1s[f][lane + 64] + v2 * W2s[f][lane + 64];
  }
  out[(size_t)node * LW + lane]      = f2bf(sigmoidf_(acc0));
  out[(size_t)node * LW + lane + 64] = f2bf(sigmoidf_(acc1));
}

// ---------------- width-128 mean aggregation, bf16, unroll x4 ----------------
__global__ void k_prop128(const ushort_t* __restrict__ h, ushort_t* __restrict__ out,
                          const int* __restrict__ row_start, const int* __restrict__ csr_src,
                          const float* __restrict__ inv_deg) {
  int t = threadIdx.x;
  int g = blockIdx.x * 4 + (t >> 6);
  int lane = t & 63;
  int s0 = row_start[g], s1 = row_start[g + 1];
  float a0 = 0.0f, a1 = 0.0f;
  int e = s0;
  for (; e + 4 <= s1; e += 4) {
    int i0 = csr_src[e], i1 = csr_src[e+1], i2 = csr_src[e+2], i3 = csr_src[e+3];
    uint_t u0 = *(const uint_t*)(h + (size_t)i0 * LW + 2 * lane);
    uint_t u1 = *(const uint_t*)(h + (size_t)i1 * LW + 2 * lane);
    uint_t u2 = *(const uint_t*)(h + (size_t)i2 * LW + 2 * lane);
    uint_t u3 = *(const uint_t*)(h + (size_t)i3 * LW + 2 * lane);
    a0 += bf2f((unsigned short)(u0 & 0xFFFF)) + bf2f((unsigned short)(u1 & 0xFFFF))
        + bf2f((unsigned short)(u2 & 0xFFFF)) + bf2f((unsigned short)(u3 & 0xFFFF));
    a1 += bf2f((unsigned short)(u0 >> 16)) + bf2f((unsigned short)(u1 >> 16))
        + bf2f((unsigned short)(u2 >> 16)) + bf2f((unsigned short)(u3 >> 16));
  }
  for (; e < s1; ++e) {
    uint_t u = *(const uint_t*)(h + (size_t)csr_src[e] * LW + 2 * lane);
    a0 += bf2f((unsigned short)(u & 0xFFFF));
    a1 += bf2f((unsigned short)(u >> 16));
  }
  float idg = inv_deg[g];
  *(uint_t*)(out + (size_t)g * LW + 2 * lane) = pack2(a0 * idg, a1 * idg);
}

// ---------------- weight conversion: Wt[n][k] = (k<128 ? Wl[k][n] : Wr[k-128][n]) bf16 ----------------
__global__ void k_convW(const float* __restrict__ Wl, const float* __restrict__ Wr,
                        ushort_t* __restrict__ Wt) {
  int idx = blockIdx.x * 256 + threadIdx.x;   // over 128*256
  int n = idx >> 8, k = idx & 255;
  float v = (k < 128) ? Wl[k * 128 + n] : Wr[(k - 128) * 128 + n];
  Wt[idx] = f2bf(v);
}

// ---------------- MFMA SAGE GEMM ----------------
__global__ __launch_bounds__(256) void k_gemm128_mfma(
    const ushort_t* __restrict__ A1, const ushort_t* __restrict__ A2,
    const ushort_t* __restrict__ Wt,   // [128][256] bf16, Wt[n][k]
    const float* __restrict__ bias, ushort_t* __restrict__ out) {
  int tid = threadIdx.x;
  int wave = tid >> 6, lane = tid & 63;
  int row0 = blockIdx.x * 64 + wave * 16;
  int r = lane & 15, kg = lane >> 4;
  f32x4v acc[8];
  #pragma unroll
  for (int nt = 0; nt < 8; ++nt) acc[nt] = (f32x4v){0.f, 0.f, 0.f, 0.f};
  #pragma unroll
  for (int ks = 0; ks < 8; ++ks) {
    const ushort_t* asrc = (ks < 4)
        ? (A1 + (size_t)(row0 + r) * LW + ks * 32 + kg * 8)
        : (A2 + (size_t)(row0 + r) * LW + (ks - 4) * 32 + kg * 8);
    bf16x8v a = *(const bf16x8v*)asrc;
    #pragma unroll
    for (int nt = 0; nt < 8; ++nt) {
      bf16x8v b = *(const bf16x8v*)(Wt + (size_t)(nt * 16 + r) * 256 + ks * 32 + kg * 8);
      acc[nt] = __builtin_amdgcn_mfma_f32_16x16x32_bf16(a, b, acc[nt], 0, 0, 0);
    }
  }
  #pragma unroll
  for (int nt = 0; nt < 8; ++nt) {
    #pragma unroll
    for (int j = 0; j < 4; ++j) {
      float v = sigmoidf_(acc[nt][j] + bias[nt * 16 + r]);
      out[(size_t)(row0 + kg * 4 + j) * LW + nt * 16 + r] = f2bf(v);
    }
  }
}

// ---------------- SAGE layer 6: width-1 transforms then aggregate ----------------
__global__ void k_wide_to1(const ushort_t* __restrict__ H, const float* __restrict__ Wl3,
                           const float* __restrict__ Wr3, float* __restrict__ g_l,
                           float* __restrict__ g_r) {
  int wave = (blockIdx.x * 256 + threadIdx.x) >> 6;
  int lane = threadIdx.x & 63;
  unsigned int u = *(const unsigned int*)(H + (size_t)wave * LW + 2 * lane);
  float h0 = bf2f((unsigned short)(u & 0xFFFF));
  float h1 = bf2f((unsigned short)(u >> 16));
  float al = h0 * Wl3[2 * lane] + h1 * Wl3[2 * lane + 1];
  float ar = h0 * Wr3[2 * lane] + h1 * Wr3[2 * lane + 1];
  #pragma unroll
  for (int off = 32; off; off >>= 1) {
    al += __shfl_xor(al, off);
    ar += __shfl_xor(ar, off);
  }
  if (lane == 0) { g_l[wave] = al; g_r[wave] = ar; }
}

__global__ void k_sage_final(const float* __restrict__ g_l, const float* __restrict__ g_r,
                             const float* __restrict__ b3, const int* __restrict__ row_start,
                             const int* __restrict__ csr_src, const float* __restrict__ inv_deg,
                             float* __restrict__ x1) {
  int i = blockIdx.x * 256 + threadIdx.x;
  int e0 = row_start[i], e1 = row_start[i + 1];
  float s = 0.0f;
  int e = e0;
  for (; e + 4 <= e1; e += 4) {
    float w0 = g_l[csr_src[e]], w1 = g_l[csr_src[e+1]];
    float w2 = g_l[csr_src[e+2]], w3 = g_l[csr_src[e+3]];
    s += (w0 + w1) + (w2 + w3);
  }
  for (; e < e1; ++e) s += g_l[csr_src[e]];
  float v = s * inv_deg[i] + g_r[i] + b3[0];
  x1[i] = fmaxf(v, 0.0f);
}

// ---------------- TAG Horner hop (width 16, bf16), thread-per-node, unroll x4 ----------------
// mode 0: o = dinv*(T·Wk);  mode 1: o = dinv*(T·Wk + dinv*gather);  mode 2: o = sigmoid(T·Wk + dinv*gather + bias)
__global__ __launch_bounds__(256) void k_tag_hh(
    const ushort_t* __restrict__ T, const float* __restrict__ W, int win,
    const ushort_t* __restrict__ w_in, ushort_t* __restrict__ w_out,
    const float* __restrict__ bias, int mode,
    const int* __restrict__ row_start, const int* __restrict__ csr_src,
    const float* __restrict__ dinv) {
  __shared__ float Ws[16][16];
  int t = threadIdx.x;
  { int rr = t >> 4, c = t & 15; Ws[rr][c] = (rr < win && c < TW) ? W[rr * TW + c] : 0.0f; }
  __syncthreads();
  int i = blockIdx.x * 256 + t;
  float di = dinv[i];
  float acc[16];
  #pragma unroll
  for (int c = 0; c < 16; ++c) acc[c] = 0.0f;

  if (mode != 0) {
    int e0 = row_start[i], e1 = row_start[i + 1];
    int e = e0;
    for (; e + 4 <= e1; e += 4) {
      int i0 = csr_src[e], i1 = csr_src[e+1], i2 = csr_src[e+2], i3 = csr_src[e+3];
      uint4 a0 = *(const uint4*)(w_in + (size_t)i0 * 16);
      uint4 a1 = *(const uint4*)(w_in + (size_t)i0 * 16 + 8);
      uint4 b0 = *(const uint4*)(w_in + (size_t)i1 * 16);
      uint4 b1 = *(const uint4*)(w_in + (size_t)i1 * 16 + 8);
      uint4 c0 = *(const uint4*)(w_in + (size_t)i2 * 16);
      uint4 c1 = *(const uint4*)(w_in + (size_t)i2 * 16 + 8);
      uint4 d0 = *(const uint4*)(w_in + (size_t)i3 * 16);
      uint4 d1 = *(const uint4*)(w_in + (size_t)i3 * 16 + 8);
      addrow16(acc, a0, a1);
      addrow16(acc, b0, b1);
      addrow16(acc, c0, c1);
      addrow16(acc, d0, d1);
    }
    for (; e < e1; ++e) {
      int i0 = csr_src[e];
      uint4 a0 = *(const uint4*)(w_in + (size_t)i0 * 16);
      uint4 a1 = *(const uint4*)(w_in + (size_t)i0 * 16 + 8);
      addrow16(acc, a0, a1);
    }
    #pragma unroll
    for (int c = 0; c < 16; ++c) acc[c] *= di;
  }

  // matvec: acc[c] += sum_f T[i][f] * Ws[f][c]
  uint4 t0 = *(const uint4*)(T + (size_t)i * 16);
  uint4 t1 = *(const uint4*)(T + (size_t)i * 16 + 8);
  float tv[16];
  tv[0]=bf2f((unsigned short)(t0.x&0xFFFF)); tv[1]=bf2f((unsigned short)(t0.x>>16));
  tv[2]=bf2f((unsigned short)(t0.y&0xFFFF)); tv[3]=bf2f((unsigned short)(t0.y>>16));
  tv[4]=bf2f((unsigned short)(t0.z&0xFFFF)); tv[5]=bf2f((unsigned short)(t0.z>>16));
  tv[6]=bf2f((unsigned short)(t0.w&0xFFFF)); tv[7]=bf2f((unsigned short)(t0.w>>16));
  tv[8]=bf2f((unsigned short)(t1.x&0xFFFF)); tv[9]=bf2f((unsigned short)(t1.x>>16));
  tv[10]=bf2f((unsigned short)(t1.y&0xFFFF)); tv[11]=bf2f((unsigned short)(t1.y>>16));
  tv[12]=bf2f((unsigned short)(t1.z&0xFFFF)); tv[13]=bf2f((unsigned short)(t1.z>>16));
  tv[14]=bf2f((unsigned short)(t1.w&0xFFFF)); tv[15]=bf2f((unsigned short)(t1.w>>16));
  #pragma unroll
  for (int f = 0; f < 16; ++f) {
    float tf = tv[f];
    const float4* wr = (const float4*)Ws[f];
    float4 w0 = wr[0], w1 = wr[1], w2 = wr[2], w3 = wr[3];
    acc[0]+=tf*w0.x; acc[1]+=tf*w0.y; acc[2]+=tf*w0.z; acc[3]+=tf*w0.w;
    acc[4]+=tf*w1.x; acc[5]+=tf*w1.y; acc[6]+=tf*w1.z; acc[7]+=tf*w1.w;
    acc[8]+=tf*w2.x; acc[9]+=tf*w2.y; acc[10]+=tf*w2.z; acc[11]+=tf*w2.w;
    acc[12]+=tf*w3.x; acc[13]+=tf*w3.y; acc[14]+=tf*w3.z; acc[15]+=tf*w3.w;
  }

  uint_t o[8];
  if (mode == 2) {
    #pragma unroll
    for (int q = 0; q < 8; ++q) {
      float v0 = (2*q   < TW) ? sigmoidf_(acc[2*q]   + bias[2*q])   : 0.0f;
      float v1 = (2*q+1 < TW) ? sigmoidf_(acc[2*q+1] + bias[2*q+1]) : 0.0f;
      o[q] = pack2(v0, v1);
    }
  } else {
    #pragma unroll
    for (int q = 0; q < 8; ++q) o[q] = pack2(di * acc[2*q], di * acc[2*q+1]);
  }
  uint4* dst = (uint4*)(w_out + (size_t)i * 16);
  dst[0] = make_uint4(o[0], o[1], o[2], o[3]);
  dst[1] = make_uint4(o[4], o[5], o[6], o[7]);
}

// ---------------- TAG layer 6: g_k = T @ Wt3[k], k-major (T bf16) ----------------
__global__ void k_tag_g(const ushort_t* __restrict__ T, const float* __restrict__ Wt3,
                        float* __restrict__ gT) {
  __shared__ float Ws[16 * TW];
  int t = threadIdx.x;
  if (t < 16 * TW) Ws[t] = Wt3[t];
  __syncthreads();
  int i = blockIdx.x * 256 + t;
  const ushort_t* tr = T + (size_t)i * 16;
  float row[TW];
  #pragma unroll
  for (int f = 0; f < TW; ++f) row[f] = bf2f(tr[f]);
  #pragma unroll
  for (int k = 0; k < 16; ++k) {
    float a = 0.0f;
    #pragma unroll
    for (int f = 0; f < TW; ++f) a += row[f] * Ws[k * TW + f];
    gT[(size_t)k * NN + i] = a;
  }
}

// ---------------- layer-6 Horner init: w = dinv ⊙ g15 ----------------
__global__ void k_scale1(const float* __restrict__ g15, const float* __restrict__ dinv,
                         float* __restrict__ w) {
  int i = blockIdx.x * 256 + threadIdx.x;
  w[i] = dinv[i] * g15[i];
}

// ---------------- layer-6 Horner hop: s = gk + dinv·Σ w[src], unroll x4 ----------------
__global__ void k_horner(const float* __restrict__ gk, const float* __restrict__ w_in,
                         float* __restrict__ w_out, int last,
                         const int* __restrict__ row_start, const int* __restrict__ csr_src,
                         const float* __restrict__ dinv) {
  int i = blockIdx.x * 256 + threadIdx.x;
  int e0 = row_start[i], e1 = row_start[i + 1];
  float gs = 0.0f;
  int e = e0;
  for (; e + 4 <= e1; e += 4) {
    float w0 = w_in[csr_src[e]],   w1 = w_in[csr_src[e+1]];
    float w2 = w_in[csr_src[e+2]], w3 = w_in[csr_src[e+3]];
    gs += (w0 + w1) + (w2 + w3);
  }
  for (; e < e1; ++e) gs += w_in[csr_src[e]];
  float s = gk[i] + dinv[i] * gs;
  w_out[i] = last ? s : dinv[i] * s;
}

// ---------------- final combine ----------------
__global__ void k_combine(const float* __restrict__ x1, const float* __restrict__ s,
                          const int* __restrict__ y, const unsigned char* __restrict__ selN,
                          const float* __restrict__ Wlin, const float* __restrict__ blin,
                          const float* __restrict__ bt3, float* __restrict__ out) {
  int i = blockIdx.x * 256 + threadIdx.x;
  float x3 = fmaxf(s[i] + bt3[0], 0.0f);
  float v = fmaxf(x1[i] * Wlin[0] + x3 * Wlin[1] + blin[0], 0.0f);
  bool z = (selN[i] != 0) && (y[i] == 0);
  out[i] = z ? 0.0f : v;
}

extern "C" void kernel_launch(void* const* d_in, const int* in_sizes, int n_in,
                              void* d_out, int out_size, void* d_ws, size_t ws_size,
                              hipStream_t stream) {
  const float* x    = (const float*)d_in[0];
  const int*   ei   = (const int*)d_in[1];
  const int*   y    = (const int*)d_in[2];
  const unsigned char* sel = (const unsigned char*)d_in[3];
  const float* Wl1  = (const float*)d_in[4];
  const float* Wr1  = (const float*)d_in[5];
  const float* b1   = (const float*)d_in[6];
  const float* Wl2  = (const float*)d_in[7];
  const float* Wr2  = (const float*)d_in[8];
  const float* b2   = (const float*)d_in[9];
  const float* Wl3  = (const float*)d_in[10];
  const float* Wr3  = (const float*)d_in[11];
  const float* b3   = (const float*)d_in[12];
  const float* Wt1  = (const float*)d_in[13];
  const float* bt1  = (const float*)d_in[14];
  const float* Wt2  = (const float*)d_in[15];
  const float* bt2  = (const float*)d_in[16];
  const float* Wt3  = (const float*)d_in[17];
  const float* bt3  = (const float*)d_in[18];
  const float* Wlin = (const float*)d_in[19];
  const float* blin = (const float*)d_in[20];

  const size_t MB = 1 << 20;
  unsigned char* w8 = (unsigned char*)d_ws;
  int*   deg       = (int*)(w8 + 0 * MB);
  int*   cursor    = (int*)(w8 + 1 * MB);
  int*   row_start = (int*)(w8 + 2 * MB);        // N+1 ints
  float* inv_deg   = (float*)(w8 + 4 * MB);
  float* dinv      = (float*)(w8 + 5 * MB);
  float* x1        = (float*)(w8 + 6 * MB);
  float* g_l       = (float*)(w8 + 7 * MB);
  float* g_r       = (float*)(w8 + 8 * MB);
  int*   btot      = (int*)(w8 + 9 * MB);
  int*   bbase     = (int*)(w8 + 9 * MB + 4096);
  int*   selflag   = (int*)(w8 + 9 * MB + 8192);
  float* sA        = (float*)(w8 + 10 * MB);
  float* w6a       = (float*)(w8 + 11 * MB);
  float* w6b       = (float*)(w8 + 12 * MB);
  unsigned char* selN = (unsigned char*)(w8 + 13 * MB);
  ushort_t* Wtc    = (ushort_t*)(w8 + 14 * MB);  // 64 KB gemm weights
  int*   csr_src   = (int*)(w8 + 16 * MB);       // 8 MiB
  float* xp        = (float*)(w8 + 24 * MB);     // 16 MiB (N x 16 fp32)
  ushort_t* xpb    = (ushort_t*)(w8 + 40 * MB);  // 8 MiB (N x 16 bf16)
  ushort_t* H      = (ushort_t*)(w8 + 48 * MB);  // 64 MiB (N x 128 bf16)
  ushort_t* AGG    = (ushort_t*)(w8 + 112 * MB); // 64 MiB -> peak 176 MiB
  float* agg16     = (float*)(w8 + 112 * MB);    // 16 MiB (overlay, dead before prop128)
  // TAG overlays (AGG region, dead after SAGE)
  ushort_t* T0  = (ushort_t*)(w8 + 112 * MB);    // 8 MiB
  ushort_t* T1  = (ushort_t*)(w8 + 120 * MB);
  ushort_t* wA  = (ushort_t*)(w8 + 128 * MB);
  ushort_t* wB  = (ushort_t*)(w8 + 136 * MB);
  float* gT     = (float*)(w8 + 144 * MB);       // 16 MiB (16 x N fp32)

  // ---- sel normalization ----
  k_selprobe<<<1, 256, 0, stream>>>(sel, selflag);
  k_norm_bool<<<NN / 256, 256, 0, stream>>>(selflag, sel, selN);
  k_norm_int<<<NN / 256, 256, 0, stream>>>(selflag, sel, selN);

  // ---- graph preprocessing ----
  hipMemsetAsync(w8, 0, 2 * MB, stream);  // deg + cursor
  k_deg<<<EE / 256, 256, 0, stream>>>(ei, deg);
  k_scan_partial<<<256, 256, 0, stream>>>(deg, btot);
  k_scan_block<<<1, 256, 0, stream>>>(btot, bbase, row_start);
  k_scan_final<<<256, 256, 0, stream>>>(deg, bbase, row_start, inv_deg, dinv);
  k_fill<<<EE / 256, 256, 0, stream>>>(ei, row_start, cursor, csr_src);
  k_pad_x<<<NN * 16 / 256, 256, 0, stream>>>(x, xp, xpb);
  k_convW<<<128, 256, 0, stream>>>(Wl2, Wr2, Wtc);

  // ---- SAGE branch ----
  k_prop16_mean<<<NN / 256, 256, 0, stream>>>(xp, agg16, row_start, csr_src, inv_deg);
  k_gemm_small<<<NN / 4, 256, 0, stream>>>(agg16, xp, Wl1, Wr1, b1, H);
  for (int l = 0; l < 4; ++l) {
    k_prop128<<<NN / 4, 256, 0, stream>>>(H, AGG, row_start, csr_src, inv_deg);
    k_gemm128_mfma<<<NN / 64, 256, 0, stream>>>(AGG, H, Wtc, b2, H);
  }
  k_wide_to1<<<NN / 4, 256, 0, stream>>>(H, Wl3, Wr3, g_l, g_r);
  k_sage_final<<<NN / 256, 256, 0, stream>>>(g_l, g_r, b3, row_start, csr_src, inv_deg, x1);

  // ---- TAG branch (Horner form) ----
  {
    const ushort_t* T = xpb;
    k_tag_hh<<<NN / 256, 256, 0, stream>>>(T, Wt1 + (size_t)15 * FIN * TW, FIN,
                                           nullptr, wA, nullptr, 0, row_start, csr_src, dinv);
    ushort_t* wi = wA; ushort_t* wo = wB;
    for (int k = 14; k >= 1; --k) {
      k_tag_hh<<<NN / 256, 256, 0, stream>>>(T, Wt1 + (size_t)k * FIN * TW, FIN,
                                             wi, wo, nullptr, 1, row_start, csr_src, dinv);
      ushort_t* tmp = wi; wi = wo; wo = tmp;
    }
    k_tag_hh<<<NN / 256, 256, 0, stream>>>(T, Wt1, FIN, wi, T0, bt1, 2,
                                           row_start, csr_src, dinv);
  }
  ushort_t* tin = T0; ushort_t* tout = T1;
  for (int l = 0; l < 4; ++l) {
    k_tag_hh<<<NN / 256, 256, 0, stream>>>(tin, Wt2 + (size_t)15 * TW * TW, TW,
                                           nullptr, wA, nullptr, 0, row_start, csr_src, dinv);
    ushort_t* wi = wA; ushort_t* wo = wB;
    for (int k = 14; k >= 1; --k) {
      k_tag_hh<<<NN / 256, 256, 0, stream>>>(tin, Wt2 + (size_t)k * TW * TW, TW,
                                             wi, wo, nullptr, 1, row_start, csr_src, dinv);
      ushort_t* tmp = wi; wi = wo; wo = tmp;
    }
    k_tag_hh<<<NN / 256, 256, 0, stream>>>(tin, Wt2, TW, wi, tout, bt2, 2,
                                           row_start, csr_src, dinv);
    ushort_t* tmp = tin; tin = tout; tout = tmp;
  }
  // layer 6
  k_tag_g<<<NN / 256, 256, 0, stream>>>(tin, Wt3, gT);
  k_scale1<<<NN / 256, 256, 0, stream>>>(gT + (size_t)15 * NN, dinv, w6a);
  float* wi = w6a; float* wo = w6b;
  for (int k = 14; k >= 0; --k) {
    int last = (k == 0) ? 1 : 0;
    float* dst = last ? sA : wo;
    k_horner<<<NN / 256, 256, 0, stream>>>(gT + (size_t)k * NN, wi, dst, last,
                                           row_start, csr_src, dinv);
    float* tmp = wi; wi = wo; wo = tmp;
  }

  // ---- combine ----
  k_combine<<<NN / 256, 256, 0, stream>>>(x1, sA, y, selN, Wlin, blin, bt3, (float*)d_out);
}